// Round 18
// baseline (251.936 us; speedup 1.0000x reference)
//
#include <hip/hip_runtime.h>
#include <hip/hip_bf16.h>

// Problem constants (fixed by reference)
#define Nn 16000
#define Ee 256000
#define Tt 5
#define GATES 512  // 4*LH
#define NREP 8     // one replica per XCD (XCC_ID-indexed)

typedef _Float16 f16;
typedef __attribute__((ext_vector_type(8))) _Float16 f16x8;
typedef __attribute__((ext_vector_type(4))) float f32x4;

// ---- workspace layout (float units) ----
#define OFF_DINV 0
#define OFF_AGGR  (OFF_DINV + Nn)              // NREP*N*5 fp32 replicas, node-major [n][t] per replica
#define OFF_DEGR  (OFF_AGGR + NREP*Nn*Tt)      // NREP*N ints
#define OFF_B0    (OFF_DEGR + NREP*Nn)         // 512
#define OFF_B1    (OFF_B0 + GATES)             // 512
#define OFF_W0S   (OFF_B1 + GATES)             // 512*192 f16 (swizzled)
#define OFF_W1S   (OFF_W0S + 512*192/2)        // 512*256 f16 (swizzled)
#define OFF_PWS   (OFF_W1S + 512*256/2)        // 64*128 f16 (swizzled head weights)
#define OFF_END   (OFF_PWS + 64*128/2)

__device__ __forceinline__ float fsig(float x) { return 1.f / (1.f + __expf(-x)); }
__device__ __forceinline__ float ftanh(float x) { return 1.f - 2.f / (1.f + __expf(2.f * x)); }

__device__ __forceinline__ unsigned xcc_id() {
    unsigned x;
    asm volatile("s_getreg_b32 %0, hwreg(HW_REG_XCC_ID)" : "=s"(x));
    return x & (NREP - 1);
}

// ---- prep: swizzle weights, fold biases, zero degr AND aggr replicas ----
// Gate-contiguous B-frag swizzle: addr = ((g*NKT + kt)*4 + gate)*512 + (quad*16+l)*8 + j
// q = gate*128 + g*16 + l ; k = kt*32 + quad*8 + j.
// grid: [0,512) W0S | [512,1024) W1S | [1024,1028) biases | [1028,1092) pwS |
//       [1092,1592) degr zero | [1592,4092) aggr zero
__global__ void prep_weights(const float* __restrict__ w_ih0, const float* __restrict__ w_hh0,
                             const float* __restrict__ b_ih0, const float* __restrict__ b_hh0,
                             const float* __restrict__ w_ih1, const float* __restrict__ w_hh1,
                             const float* __restrict__ b_ih1, const float* __restrict__ b_hh1,
                             const float* __restrict__ pw1,
                             f16* __restrict__ W0S, f16* __restrict__ W1S, f16* __restrict__ pwS,
                             float* __restrict__ B0, float* __restrict__ B1,
                             int* __restrict__ degr, float* __restrict__ aggr) {
    int b = blockIdx.x, t = threadIdx.x;
    if (b < 512) {
        if (t < 192) {
            int q = b, k = t;
            float v = (k < 64) ? w_ih0[q * 64 + k] : w_hh0[q * 128 + (k - 64)];
            int g = (q & 127) >> 4, l = q & 15, gate = q >> 7;
            int kt = k >> 5, quad = (k >> 3) & 3, j = k & 7;
            W0S[(((g * 6 + kt) * 4 + gate) * 64 + quad * 16 + l) * 8 + j] = (f16)v;
        }
    } else if (b < 1024) {
        int q = b - 512, k = t;
        float v = (k < 128) ? w_ih1[q * 128 + k] : w_hh1[q * 128 + (k - 128)];
        int g = (q & 127) >> 4, l = q & 15, gate = q >> 7;
        int kt = k >> 5, quad = (k >> 3) & 3, j = k & 7;
        W1S[(((g * 8 + kt) * 4 + gate) * 64 + quad * 16 + l) * 8 + j] = (f16)v;
    } else if (b < 1028) {
        int idx = (b - 1024) * 256 + t;
        if (idx < 512) B0[idx] = b_ih0[idx] + b_hh0[idx];
        else           B1[idx - 512] = b_ih1[idx - 512] + b_hh1[idx - 512];
    } else if (b < 1092) {
        if (t < 128) {
            int u = b - 1028, k = t;
            int g = u >> 4, lp = u & 15;
            int kt = k >> 5, quad = (k >> 3) & 3, j = k & 7;
            pwS[((g * 4 + kt) * 64 + quad * 16 + lp) * 8 + j] = (f16)pw1[u * 128 + k];
        }
    } else if (b < 1592) {
        int n = (b - 1092) * 256 + t;
        if (n < NREP * Nn) degr[n] = 0;
    } else {
        int n = (b - 1592) * 256 + t;
        if (n < NREP * Nn * Tt) aggr[n] = 0.f;
    }
}

// ---- degree count: XCD-local replica, workgroup-scope atomic (executes in local L2) ----
__global__ void deg_count(const int* __restrict__ ei, int* __restrict__ degr) {
    int e = blockIdx.x * blockDim.x + threadIdx.x;
    if (e >= Ee) return;
    int* p = &degr[xcc_id() * Nn + ei[Ee + e]];
    __hip_atomic_fetch_add(p, 1, __ATOMIC_RELAXED, __HIP_MEMORY_SCOPE_WORKGROUP);
}

// ---- dinv only (replica zero + self-term moved to prep / recur fold) ----
__global__ void dinv_kernel(const int* __restrict__ degr, float* __restrict__ dinv) {
    int n = blockIdx.x * blockDim.x + threadIdx.x;
    if (n >= Nn) return;
    int deg = 1;  // self loop
    #pragma unroll
    for (int r = 0; r < NREP; ++r) deg += degr[r * Nn + n];
    dinv[n] = rsqrtf((float)deg);
}

// ---- edge scatter: one edge/thread; adds x[s,t]*dinv[s] (dinv[d] applied at fold) ----
__global__ void edge_scatter(const float* __restrict__ x, const int* __restrict__ ei,
                             const float* __restrict__ dinv, float* __restrict__ aggr) {
    int e = blockIdx.x * blockDim.x + threadIdx.x;
    if (e >= Ee) return;
    int s = ei[e], d = ei[Ee + e];
    float ds = dinv[s];
    float* base = aggr + (size_t)xcc_id() * (Nn * Tt) + (size_t)d * Tt;
    #pragma unroll
    for (int t = 0; t < Tt; ++t) {
        float v = x[s * Tt + t] * ds;
        __hip_atomic_fetch_add(base + t, v, __ATOMIC_RELAXED, __HIP_MEMORY_SCOPE_WORKGROUP);
    }
}

// ---- fused recurrence: agg fold (+dinv[d], +self-loop) + 5x2 LSTM + head ----
// Block = 512 thr = 8 waves, 32 nodes. R15/R17 champion: VGPR 128, unroll 2 on
// LDS kt loops, ping-pong h (2 barriers/step), zero spill, recur 95 µs steady.
// Gate-contiguous W swizzle: 4 gate loads share one base (+0/1/2/3 KB imm).
// XOR-chunk h swizzle: 0 LDS bank conflicts (measured R7-R17).
__global__ __launch_bounds__(512, 2) void recur_all(
    const float* __restrict__ aggr, const float* __restrict__ dinv,
    const float* __restrict__ gw, const float* __restrict__ gb,
    const f16* __restrict__ W0S, const f16* __restrict__ W1S,
    const float* __restrict__ B0, const float* __restrict__ B1,
    const f16* __restrict__ pwS, const float* __restrict__ pb1,
    const float* __restrict__ pw2, const float* __restrict__ pb2,
    const float* __restrict__ x, float* __restrict__ out) {
    __shared__ f16 h0buf[2][32 * 128];   // ping-pong
    __shared__ f16 h1buf[2][32 * 128];
    __shared__ float sAgg[32 * Tt];      // folded agg for this block's 32 nodes
    const int tid = threadIdx.x;
    const int lane = tid & 63;
    const int uq = tid >> 6;          // wave = u16-group (0..7)
    const int l = lane & 15;
    const int quad = lane >> 4;
    const int n0 = blockIdx.x * 32;
    const int u = uq * 16 + l;        // this lane's hidden unit
    const int uch = u >> 3;           // u-chunk for LDS swizzle
    const int ulo = u & 7;

    // fold the 8 XCD replicas, apply dinv[d], add self-loop term (was agg_reduce)
    if (tid < 32 * Tt) {
        int nl = tid / Tt, t = tid - nl * Tt;
        int n = n0 + nl;
        size_t off = (size_t)n * Tt + t;
        float s = 0.f;
        #pragma unroll
        for (int r = 0; r < NREP; ++r) s += aggr[(size_t)r * (Nn * Tt) + off];
        float dv = dinv[n];
        sAgg[nl * Tt + t] = s * dv + x[off] * dv * dv;
    }

    const float bI0 = B0[u], bF0 = B0[128 + u], bG0 = B0[256 + u], bO0 = B0[384 + u];
    const float bI1 = B1[u], bF1 = B1[128 + u], bG1 = B1[256 + u], bO1 = B1[384 + u];

    f32x4 c0s[2], c1s[2];
    #pragma unroll
    for (int i = 0; i < 2; ++i) {
        c0s[i] = (f32x4){0.f, 0.f, 0.f, 0.f};
        c1s[i] = (f32x4){0.f, 0.f, 0.f, 0.f};
    }
    __syncthreads();   // sAgg visible

    f32x4 acc[2][4];
    #pragma unroll 1
    for (int t = 0; t < Tt; ++t) {
        const int cur = t & 1;        // read h[cur], write h[cur^1]
        const f16* h0r = h0buf[cur];
        const f16* h1r = h1buf[cur];
        f16* h0w = h0buf[cur ^ 1];
        f16* h1w = h1buf[cur ^ 1];

        // ======== layer 0: K = [feat(64) | h0(128)], NKT=6 ========
        #pragma unroll
        for (int i = 0; i < 2; ++i)
            #pragma unroll
            for (int g = 0; g < 4; ++g) acc[i][g] = (f32x4){0.f, 0.f, 0.f, 0.f};
        float an[2];
        #pragma unroll
        for (int i = 0; i < 2; ++i)
            an[i] = sAgg[(i * 16 + l) * Tt + t];

        // feat k-tiles (kt = 0,1): generated GCN features
        #pragma unroll
        for (int kt = 0; kt < 2; ++kt) {
            f16x8 af[2];
            #pragma unroll
            for (int j = 0; j < 8; ++j) {
                int k = kt * 32 + quad * 8 + j;
                float gwj = gw[k], gbj = gb[k];
                #pragma unroll
                for (int i = 0; i < 2; ++i)
                    af[i][j] = (f16)fmaxf(gwj * an[i] + gbj, 0.f);
            }
            const f16* bp = W0S + ((size_t)(uq * 6 + kt) * 4) * 512 + lane * 8;
            #pragma unroll
            for (int g = 0; g < 4; ++g) {
                f16x8 b = *(const f16x8*)(bp + g * 512);
                #pragma unroll
                for (int i = 0; i < 2; ++i)
                    acc[i][g] = __builtin_amdgcn_mfma_f32_16x16x32_f16(af[i], b, acc[i][g], 0, 0, 0);
            }
        }
        // h0 k-tiles (kt = 2..5): skip at t=0 (h0 zero). unroll 2: 2x loads in flight.
        if (t > 0) {
            #pragma unroll 2
            for (int kt = 2; kt < 6; ++kt) {
                int ub = (kt - 2) * 4 + quad;      // h0 u-chunk
                f16x8 af[2];
                #pragma unroll
                for (int i = 0; i < 2; ++i)
                    af[i] = *(const f16x8*)&h0r[(i * 16 + l) * 128 + ((ub ^ l) << 3)];
                const f16* bp = W0S + ((size_t)(uq * 6 + kt) * 4) * 512 + lane * 8;
                #pragma unroll
                for (int g = 0; g < 4; ++g) {
                    f16x8 b = *(const f16x8*)(bp + g * 512);
                    #pragma unroll
                    for (int i = 0; i < 2; ++i)
                        acc[i][g] = __builtin_amdgcn_mfma_f32_16x16x32_f16(af[i], b, acc[i][g], 0, 0, 0);
                }
            }
        }
        // L0 epilogue -> write h0_new into the OTHER buffer (no WAR with readers)
        #pragma unroll
        for (int i = 0; i < 2; ++i) {
            f32x4 cc = c0s[i];
            #pragma unroll
            for (int r = 0; r < 4; ++r) {
                float i_ = fsig(acc[i][0][r] + bI0);
                float f_ = fsig(acc[i][1][r] + bF0);
                float g_ = ftanh(acc[i][2][r] + bG0);
                float o_ = fsig(acc[i][3][r] + bO0);
                float cn = f_ * cc[r] + i_ * g_;
                cc[r] = cn;
                float hn = o_ * ftanh(cn);
                int node = i * 16 + quad * 4 + r;
                h0w[node * 128 + (((uch ^ (node & 15)) << 3) | ulo)] = (f16)hn;
            }
            c0s[i] = cc;
        }
        __syncthreads();   // barrier 1: h0_new visible to L1 readers

        // ======== layer 1: K = [h0_new(128) | h1(128)], NKT=8 ========
        #pragma unroll
        for (int i = 0; i < 2; ++i)
            #pragma unroll
            for (int g = 0; g < 4; ++g) acc[i][g] = (f32x4){0.f, 0.f, 0.f, 0.f};

        {
            int ktmax = (t == 0) ? 4 : 8;          // h1 zero at t=0
            #pragma unroll 2
            for (int kt = 0; kt < ktmax; ++kt) {
                const f16* hb = (kt < 4) ? h0w : h1r;   // h0_new | h1_old
                int ub = (kt & 3) * 4 + quad;
                f16x8 af[2];
                #pragma unroll
                for (int i = 0; i < 2; ++i)
                    af[i] = *(const f16x8*)&hb[(i * 16 + l) * 128 + ((ub ^ l) << 3)];
                const f16* bp = W1S + ((size_t)(uq * 8 + kt) * 4) * 512 + lane * 8;
                #pragma unroll
                for (int g = 0; g < 4; ++g) {
                    f16x8 b = *(const f16x8*)(bp + g * 512);
                    #pragma unroll
                    for (int i = 0; i < 2; ++i)
                        acc[i][g] = __builtin_amdgcn_mfma_f32_16x16x32_f16(af[i], b, acc[i][g], 0, 0, 0);
                }
            }
        }
        // L1 epilogue -> write h1_new into the OTHER buffer
        #pragma unroll
        for (int i = 0; i < 2; ++i) {
            f32x4 cc = c1s[i];
            #pragma unroll
            for (int r = 0; r < 4; ++r) {
                float i_ = fsig(acc[i][0][r] + bI1);
                float f_ = fsig(acc[i][1][r] + bF1);
                float g_ = ftanh(acc[i][2][r] + bG1);
                float o_ = fsig(acc[i][3][r] + bO1);
                float cn = f_ * cc[r] + i_ * g_;
                cc[r] = cn;
                float hn = o_ * ftanh(cn);
                int node = i * 16 + quad * 4 + r;
                h1w[node * 128 + (((uch ^ (node & 15)) << 3) | ulo)] = (f16)hn;
            }
            c1s[i] = cc;
        }
        __syncthreads();   // barrier 2: h1_new visible to next step's readers
    }

    // ======== head: out = x[:,4] + relu(h1@pw1.T+pb1)@pw2.T + pb2 ========
    // last step (t=4, cur=0) wrote h1buf[1]; waves 0..1 handle 16 nodes each
    const f16* h1f = h1buf[1];   // Tt=5 -> final h1 in buffer 1
    if (uq < 2) {
        f32x4 hacc[4];
        #pragma unroll
        for (int g = 0; g < 4; ++g) hacc[g] = (f32x4){0.f, 0.f, 0.f, 0.f};
        #pragma unroll
        for (int kt = 0; kt < 4; ++kt) {
            int ub = kt * 4 + quad;
            f16x8 a = *(const f16x8*)&h1f[(uq * 16 + l) * 128 + ((ub ^ l) << 3)];
            #pragma unroll
            for (int g = 0; g < 4; ++g) {
                f16x8 b = *(const f16x8*)(pwS + (size_t)(g * 4 + kt) * 512 + lane * 8);
                hacc[g] = __builtin_amdgcn_mfma_f32_16x16x32_f16(a, b, hacc[g], 0, 0, 0);
            }
        }
        float yr[4] = {0.f, 0.f, 0.f, 0.f};
        #pragma unroll
        for (int g = 0; g < 4; ++g) {
            float pb = pb1[g * 16 + l];
            float pw = pw2[g * 16 + l];
            #pragma unroll
            for (int r = 0; r < 4; ++r)
                yr[r] += fmaxf(hacc[g][r] + pb, 0.f) * pw;
        }
        #pragma unroll
        for (int m = 1; m <= 8; m <<= 1) {
            #pragma unroll
            for (int r = 0; r < 4; ++r) yr[r] += __shfl_xor(yr[r], m);
        }
        if (l < 4) {
            float v = (l == 0) ? yr[0] : (l == 1) ? yr[1] : (l == 2) ? yr[2] : yr[3];
            int node = n0 + uq * 16 + quad * 4 + l;
            out[node] = x[node * Tt + (Tt - 1)] + v + pb2[0];
        }
    }
}

extern "C" void kernel_launch(void* const* d_in, const int* in_sizes, int n_in,
                              void* d_out, int out_size, void* d_ws, size_t ws_size,
                              hipStream_t stream) {
    const float* x      = (const float*)d_in[0];
    const int*   ei     = (const int*)d_in[1];
    const float* gcn_w  = (const float*)d_in[2];
    const float* gcn_b  = (const float*)d_in[3];
    const float* w_ih0  = (const float*)d_in[4];
    const float* w_hh0  = (const float*)d_in[5];
    const float* b_ih0  = (const float*)d_in[6];
    const float* b_hh0  = (const float*)d_in[7];
    const float* w_ih1  = (const float*)d_in[8];
    const float* w_hh1  = (const float*)d_in[9];
    const float* b_ih1  = (const float*)d_in[10];
    const float* b_hh1  = (const float*)d_in[11];
    const float* pw1    = (const float*)d_in[12];
    const float* pb1    = (const float*)d_in[13];
    const float* pw2    = (const float*)d_in[14];
    const float* pb2    = (const float*)d_in[15];
    float* out = (float*)d_out;

    float* wsf  = (float*)d_ws;
    float* dinv = wsf + OFF_DINV;
    float* aggr = wsf + OFF_AGGR;
    int*   degr = (int*)(wsf + OFF_DEGR);
    float* B0   = wsf + OFF_B0;
    float* B1   = wsf + OFF_B1;
    f16*   W0S  = (f16*)(wsf + OFF_W0S);
    f16*   W1S  = (f16*)(wsf + OFF_W1S);
    f16*   pwS  = (f16*)(wsf + OFF_PWS);

    // 1) prep: weights (swizzled) + biases + zero degr/aggr replicas
    prep_weights<<<4092, 256, 0, stream>>>(w_ih0, w_hh0, b_ih0, b_hh0,
                                           w_ih1, w_hh1, b_ih1, b_hh1, pw1,
                                           W0S, W1S, pwS, B0, B1, degr, aggr);
    // 2) degree (XCD-local atomics)
    deg_count<<<(Ee + 255) / 256, 256, 0, stream>>>(ei, degr);
    // 3) dinv
    dinv_kernel<<<(Nn + 255) / 256, 256, 0, stream>>>(degr, dinv);
    // 4) edge scatter: one edge/thread, 5 XCD-local atomics, dinv[s] only
    edge_scatter<<<(Ee + 255) / 256, 256, 0, stream>>>(x, ei, dinv, aggr);

    // 5) fused recurrence (incl. agg fold + dinv[d] + self-loop): LSTM + head
    recur_all<<<Nn / 32, 512, 0, stream>>>(aggr, dinv, gcn_w, gcn_b, W0S, W1S, B0, B1,
                                           pwS, pb1, pw2, pb2, x, out);
}

// Round 19
// 203.127 us; speedup vs baseline: 1.2403x; 1.2403x over previous
//
#include <hip/hip_runtime.h>
#include <hip/hip_bf16.h>

// Problem constants (fixed by reference)
#define Nn 16000
#define Ee 256000
#define Tt 5
#define GATES 512  // 4*LH
#define NREP 8     // one replica per XCD (XCC_ID-indexed)

typedef _Float16 f16;
typedef __attribute__((ext_vector_type(8))) _Float16 f16x8;
typedef __attribute__((ext_vector_type(4))) float f32x4;

// ---- workspace layout (float units) ----
#define OFF_DINV 0
#define OFF_AGGR  (OFF_DINV + Nn)              // NREP*N*5 fp32 replicas, node-major [n][t] per replica
#define OFF_DEGR  (OFF_AGGR + NREP*Nn*Tt)      // NREP*N ints
#define OFF_B0    (OFF_DEGR + NREP*Nn)         // 512
#define OFF_B1    (OFF_B0 + GATES)             // 512
#define OFF_W0S   (OFF_B1 + GATES)             // 512*192 f16 (swizzled)
#define OFF_W1S   (OFF_W0S + 512*192/2)        // 512*256 f16 (swizzled)
#define OFF_PWS   (OFF_W1S + 512*256/2)        // 64*128 f16 (swizzled head weights)
#define OFF_END   (OFF_PWS + 64*128/2)

__device__ __forceinline__ float fsig(float x) { return 1.f / (1.f + __expf(-x)); }
__device__ __forceinline__ float ftanh(float x) { return 1.f - 2.f / (1.f + __expf(2.f * x)); }

__device__ __forceinline__ unsigned xcc_id() {
    unsigned x;
    asm volatile("s_getreg_b32 %0, hwreg(HW_REG_XCC_ID)" : "=s"(x));
    return x & (NREP - 1);
}

// ---- prep: swizzle weights, fold biases, zero degr AND aggr replicas ----
// Gate-contiguous B-frag swizzle: addr = ((g*NKT + kt)*4 + gate)*512 + (quad*16+l)*8 + j
// q = gate*128 + g*16 + l ; k = kt*32 + quad*8 + j.
// grid: [0,512) W0S | [512,1024) W1S | [1024,1028) biases | [1028,1092) pwS |
//       [1092,1592) degr zero | [1592,4092) aggr zero
__global__ void prep_weights(const float* __restrict__ w_ih0, const float* __restrict__ w_hh0,
                             const float* __restrict__ b_ih0, const float* __restrict__ b_hh0,
                             const float* __restrict__ w_ih1, const float* __restrict__ w_hh1,
                             const float* __restrict__ b_ih1, const float* __restrict__ b_hh1,
                             const float* __restrict__ pw1,
                             f16* __restrict__ W0S, f16* __restrict__ W1S, f16* __restrict__ pwS,
                             float* __restrict__ B0, float* __restrict__ B1,
                             int* __restrict__ degr, float* __restrict__ aggr) {
    int b = blockIdx.x, t = threadIdx.x;
    if (b < 512) {
        if (t < 192) {
            int q = b, k = t;
            float v = (k < 64) ? w_ih0[q * 64 + k] : w_hh0[q * 128 + (k - 64)];
            int g = (q & 127) >> 4, l = q & 15, gate = q >> 7;
            int kt = k >> 5, quad = (k >> 3) & 3, j = k & 7;
            W0S[(((g * 6 + kt) * 4 + gate) * 64 + quad * 16 + l) * 8 + j] = (f16)v;
        }
    } else if (b < 1024) {
        int q = b - 512, k = t;
        float v = (k < 128) ? w_ih1[q * 128 + k] : w_hh1[q * 128 + (k - 128)];
        int g = (q & 127) >> 4, l = q & 15, gate = q >> 7;
        int kt = k >> 5, quad = (k >> 3) & 3, j = k & 7;
        W1S[(((g * 8 + kt) * 4 + gate) * 64 + quad * 16 + l) * 8 + j] = (f16)v;
    } else if (b < 1028) {
        int idx = (b - 1024) * 256 + t;
        if (idx < 512) B0[idx] = b_ih0[idx] + b_hh0[idx];
        else           B1[idx - 512] = b_ih1[idx - 512] + b_hh1[idx - 512];
    } else if (b < 1092) {
        if (t < 128) {
            int u = b - 1028, k = t;
            int g = u >> 4, lp = u & 15;
            int kt = k >> 5, quad = (k >> 3) & 3, j = k & 7;
            pwS[((g * 4 + kt) * 64 + quad * 16 + lp) * 8 + j] = (f16)pw1[u * 128 + k];
        }
    } else if (b < 1592) {
        int n = (b - 1092) * 256 + t;
        if (n < NREP * Nn) degr[n] = 0;
    } else {
        int n = (b - 1592) * 256 + t;
        if (n < NREP * Nn * Tt) aggr[n] = 0.f;
    }
}

// ---- degree count: XCD-local replica, workgroup-scope atomic (executes in local L2) ----
__global__ void deg_count(const int* __restrict__ ei, int* __restrict__ degr) {
    int e = blockIdx.x * blockDim.x + threadIdx.x;
    if (e >= Ee) return;
    int* p = &degr[xcc_id() * Nn + ei[Ee + e]];
    __hip_atomic_fetch_add(p, 1, __ATOMIC_RELAXED, __HIP_MEMORY_SCOPE_WORKGROUP);
}

// ---- dinv ----
__global__ void dinv_kernel(const int* __restrict__ degr, float* __restrict__ dinv) {
    int n = blockIdx.x * blockDim.x + threadIdx.x;
    if (n >= Nn) return;
    int deg = 1;  // self loop
    #pragma unroll
    for (int r = 0; r < NREP; ++r) deg += degr[r * Nn + n];
    dinv[n] = rsqrtf((float)deg);
}

// ---- edge scatter: one (edge,t) per thread — 1 independent atomic each.
// R17/R18's one-edge-per-thread form (5 atomics to the same cacheline)
// serialized at the L2 bank and cost ~45 µs of total; this reverts it.
// Adds x[s,t]*dinv[s]; dinv[d] is applied at the recur fold. ----
__global__ void edge_scatter(const float* __restrict__ x, const int* __restrict__ ei,
                             const float* __restrict__ dinv, float* __restrict__ aggr) {
    int idx = blockIdx.x * blockDim.x + threadIdx.x;
    if (idx >= Ee * Tt) return;
    int e = idx / Tt, t = idx - e * Tt;
    int s = ei[e], d = ei[Ee + e];
    float v = x[s * Tt + t] * dinv[s];
    float* p = aggr + (size_t)xcc_id() * (Nn * Tt) + (size_t)d * Tt + t;
    __hip_atomic_fetch_add(p, v, __ATOMIC_RELAXED, __HIP_MEMORY_SCOPE_WORKGROUP);
}

// ---- fused recurrence: agg fold (+dinv[d], +self-loop) + 5x2 LSTM + head ----
// Block = 512 thr = 8 waves, 32 nodes. Champion config (95 µs steady, R17/R18):
// VGPR 128, unroll 2 on LDS kt loops, ping-pong h (2 barriers/step), no spill.
// Gate-contiguous W swizzle: 4 gate loads share one base (+0/1/2/3 KB imm).
// XOR-chunk h swizzle: 0 LDS bank conflicts (measured R7-R18).
__global__ __launch_bounds__(512, 2) void recur_all(
    const float* __restrict__ aggr, const float* __restrict__ dinv,
    const float* __restrict__ gw, const float* __restrict__ gb,
    const f16* __restrict__ W0S, const f16* __restrict__ W1S,
    const float* __restrict__ B0, const float* __restrict__ B1,
    const f16* __restrict__ pwS, const float* __restrict__ pb1,
    const float* __restrict__ pw2, const float* __restrict__ pb2,
    const float* __restrict__ x, float* __restrict__ out) {
    __shared__ f16 h0buf[2][32 * 128];   // ping-pong
    __shared__ f16 h1buf[2][32 * 128];
    __shared__ float sAgg[32 * Tt];      // folded agg for this block's 32 nodes
    const int tid = threadIdx.x;
    const int lane = tid & 63;
    const int uq = tid >> 6;          // wave = u16-group (0..7)
    const int l = lane & 15;
    const int quad = lane >> 4;
    const int n0 = blockIdx.x * 32;
    const int u = uq * 16 + l;        // this lane's hidden unit
    const int uch = u >> 3;           // u-chunk for LDS swizzle
    const int ulo = u & 7;

    // fold the 8 XCD replicas, apply dinv[d], add self-loop term
    if (tid < 32 * Tt) {
        int nl = tid / Tt, t = tid - nl * Tt;
        int n = n0 + nl;
        size_t off = (size_t)n * Tt + t;
        float s = 0.f;
        #pragma unroll
        for (int r = 0; r < NREP; ++r) s += aggr[(size_t)r * (Nn * Tt) + off];
        float dv = dinv[n];
        sAgg[nl * Tt + t] = s * dv + x[off] * dv * dv;
    }

    const float bI0 = B0[u], bF0 = B0[128 + u], bG0 = B0[256 + u], bO0 = B0[384 + u];
    const float bI1 = B1[u], bF1 = B1[128 + u], bG1 = B1[256 + u], bO1 = B1[384 + u];

    f32x4 c0s[2], c1s[2];
    #pragma unroll
    for (int i = 0; i < 2; ++i) {
        c0s[i] = (f32x4){0.f, 0.f, 0.f, 0.f};
        c1s[i] = (f32x4){0.f, 0.f, 0.f, 0.f};
    }
    __syncthreads();   // sAgg visible

    f32x4 acc[2][4];
    #pragma unroll 1
    for (int t = 0; t < Tt; ++t) {
        const int cur = t & 1;        // read h[cur], write h[cur^1]
        const f16* h0r = h0buf[cur];
        const f16* h1r = h1buf[cur];
        f16* h0w = h0buf[cur ^ 1];
        f16* h1w = h1buf[cur ^ 1];

        // ======== layer 0: K = [feat(64) | h0(128)], NKT=6 ========
        #pragma unroll
        for (int i = 0; i < 2; ++i)
            #pragma unroll
            for (int g = 0; g < 4; ++g) acc[i][g] = (f32x4){0.f, 0.f, 0.f, 0.f};
        float an[2];
        #pragma unroll
        for (int i = 0; i < 2; ++i)
            an[i] = sAgg[(i * 16 + l) * Tt + t];

        // feat k-tiles (kt = 0,1): generated GCN features
        #pragma unroll
        for (int kt = 0; kt < 2; ++kt) {
            f16x8 af[2];
            #pragma unroll
            for (int j = 0; j < 8; ++j) {
                int k = kt * 32 + quad * 8 + j;
                float gwj = gw[k], gbj = gb[k];
                #pragma unroll
                for (int i = 0; i < 2; ++i)
                    af[i][j] = (f16)fmaxf(gwj * an[i] + gbj, 0.f);
            }
            const f16* bp = W0S + ((size_t)(uq * 6 + kt) * 4) * 512 + lane * 8;
            #pragma unroll
            for (int g = 0; g < 4; ++g) {
                f16x8 b = *(const f16x8*)(bp + g * 512);
                #pragma unroll
                for (int i = 0; i < 2; ++i)
                    acc[i][g] = __builtin_amdgcn_mfma_f32_16x16x32_f16(af[i], b, acc[i][g], 0, 0, 0);
            }
        }
        // h0 k-tiles (kt = 2..5): skip at t=0 (h0 zero). unroll 2: 2x loads in flight.
        if (t > 0) {
            #pragma unroll 2
            for (int kt = 2; kt < 6; ++kt) {
                int ub = (kt - 2) * 4 + quad;      // h0 u-chunk
                f16x8 af[2];
                #pragma unroll
                for (int i = 0; i < 2; ++i)
                    af[i] = *(const f16x8*)&h0r[(i * 16 + l) * 128 + ((ub ^ l) << 3)];
                const f16* bp = W0S + ((size_t)(uq * 6 + kt) * 4) * 512 + lane * 8;
                #pragma unroll
                for (int g = 0; g < 4; ++g) {
                    f16x8 b = *(const f16x8*)(bp + g * 512);
                    #pragma unroll
                    for (int i = 0; i < 2; ++i)
                        acc[i][g] = __builtin_amdgcn_mfma_f32_16x16x32_f16(af[i], b, acc[i][g], 0, 0, 0);
                }
            }
        }
        // L0 epilogue -> write h0_new into the OTHER buffer (no WAR with readers)
        #pragma unroll
        for (int i = 0; i < 2; ++i) {
            f32x4 cc = c0s[i];
            #pragma unroll
            for (int r = 0; r < 4; ++r) {
                float i_ = fsig(acc[i][0][r] + bI0);
                float f_ = fsig(acc[i][1][r] + bF0);
                float g_ = ftanh(acc[i][2][r] + bG0);
                float o_ = fsig(acc[i][3][r] + bO0);
                float cn = f_ * cc[r] + i_ * g_;
                cc[r] = cn;
                float hn = o_ * ftanh(cn);
                int node = i * 16 + quad * 4 + r;
                h0w[node * 128 + (((uch ^ (node & 15)) << 3) | ulo)] = (f16)hn;
            }
            c0s[i] = cc;
        }
        __syncthreads();   // barrier 1: h0_new visible to L1 readers

        // ======== layer 1: K = [h0_new(128) | h1(128)], NKT=8 ========
        #pragma unroll
        for (int i = 0; i < 2; ++i)
            #pragma unroll
            for (int g = 0; g < 4; ++g) acc[i][g] = (f32x4){0.f, 0.f, 0.f, 0.f};

        {
            int ktmax = (t == 0) ? 4 : 8;          // h1 zero at t=0
            #pragma unroll 2
            for (int kt = 0; kt < ktmax; ++kt) {
                const f16* hb = (kt < 4) ? h0w : h1r;   // h0_new | h1_old
                int ub = (kt & 3) * 4 + quad;
                f16x8 af[2];
                #pragma unroll
                for (int i = 0; i < 2; ++i)
                    af[i] = *(const f16x8*)&hb[(i * 16 + l) * 128 + ((ub ^ l) << 3)];
                const f16* bp = W1S + ((size_t)(uq * 8 + kt) * 4) * 512 + lane * 8;
                #pragma unroll
                for (int g = 0; g < 4; ++g) {
                    f16x8 b = *(const f16x8*)(bp + g * 512);
                    #pragma unroll
                    for (int i = 0; i < 2; ++i)
                        acc[i][g] = __builtin_amdgcn_mfma_f32_16x16x32_f16(af[i], b, acc[i][g], 0, 0, 0);
                }
            }
        }
        // L1 epilogue -> write h1_new into the OTHER buffer
        #pragma unroll
        for (int i = 0; i < 2; ++i) {
            f32x4 cc = c1s[i];
            #pragma unroll
            for (int r = 0; r < 4; ++r) {
                float i_ = fsig(acc[i][0][r] + bI1);
                float f_ = fsig(acc[i][1][r] + bF1);
                float g_ = ftanh(acc[i][2][r] + bG1);
                float o_ = fsig(acc[i][3][r] + bO1);
                float cn = f_ * cc[r] + i_ * g_;
                cc[r] = cn;
                float hn = o_ * ftanh(cn);
                int node = i * 16 + quad * 4 + r;
                h1w[node * 128 + (((uch ^ (node & 15)) << 3) | ulo)] = (f16)hn;
            }
            c1s[i] = cc;
        }
        __syncthreads();   // barrier 2: h1_new visible to next step's readers
    }

    // ======== head: out = x[:,4] + relu(h1@pw1.T+pb1)@pw2.T + pb2 ========
    // last step (t=4, cur=0) wrote h1buf[1]; waves 0..1 handle 16 nodes each
    const f16* h1f = h1buf[1];   // Tt=5 -> final h1 in buffer 1
    if (uq < 2) {
        f32x4 hacc[4];
        #pragma unroll
        for (int g = 0; g < 4; ++g) hacc[g] = (f32x4){0.f, 0.f, 0.f, 0.f};
        #pragma unroll
        for (int kt = 0; kt < 4; ++kt) {
            int ub = kt * 4 + quad;
            f16x8 a = *(const f16x8*)&h1f[(uq * 16 + l) * 128 + ((ub ^ l) << 3)];
            #pragma unroll
            for (int g = 0; g < 4; ++g) {
                f16x8 b = *(const f16x8*)(pwS + (size_t)(g * 4 + kt) * 512 + lane * 8);
                hacc[g] = __builtin_amdgcn_mfma_f32_16x16x32_f16(a, b, hacc[g], 0, 0, 0);
            }
        }
        float yr[4] = {0.f, 0.f, 0.f, 0.f};
        #pragma unroll
        for (int g = 0; g < 4; ++g) {
            float pb = pb1[g * 16 + l];
            float pw = pw2[g * 16 + l];
            #pragma unroll
            for (int r = 0; r < 4; ++r)
                yr[r] += fmaxf(hacc[g][r] + pb, 0.f) * pw;
        }
        #pragma unroll
        for (int m = 1; m <= 8; m <<= 1) {
            #pragma unroll
            for (int r = 0; r < 4; ++r) yr[r] += __shfl_xor(yr[r], m);
        }
        if (l < 4) {
            float v = (l == 0) ? yr[0] : (l == 1) ? yr[1] : (l == 2) ? yr[2] : yr[3];
            int node = n0 + uq * 16 + quad * 4 + l;
            out[node] = x[node * Tt + (Tt - 1)] + v + pb2[0];
        }
    }
}

extern "C" void kernel_launch(void* const* d_in, const int* in_sizes, int n_in,
                              void* d_out, int out_size, void* d_ws, size_t ws_size,
                              hipStream_t stream) {
    const float* x      = (const float*)d_in[0];
    const int*   ei     = (const int*)d_in[1];
    const float* gcn_w  = (const float*)d_in[2];
    const float* gcn_b  = (const float*)d_in[3];
    const float* w_ih0  = (const float*)d_in[4];
    const float* w_hh0  = (const float*)d_in[5];
    const float* b_ih0  = (const float*)d_in[6];
    const float* b_hh0  = (const float*)d_in[7];
    const float* w_ih1  = (const float*)d_in[8];
    const float* w_hh1  = (const float*)d_in[9];
    const float* b_ih1  = (const float*)d_in[10];
    const float* b_hh1  = (const float*)d_in[11];
    const float* pw1    = (const float*)d_in[12];
    const float* pb1    = (const float*)d_in[13];
    const float* pw2    = (const float*)d_in[14];
    const float* pb2    = (const float*)d_in[15];
    float* out = (float*)d_out;

    float* wsf  = (float*)d_ws;
    float* dinv = wsf + OFF_DINV;
    float* aggr = wsf + OFF_AGGR;
    int*   degr = (int*)(wsf + OFF_DEGR);
    float* B0   = wsf + OFF_B0;
    float* B1   = wsf + OFF_B1;
    f16*   W0S  = (f16*)(wsf + OFF_W0S);
    f16*   W1S  = (f16*)(wsf + OFF_W1S);
    f16*   pwS  = (f16*)(wsf + OFF_PWS);

    // 1) prep: weights (swizzled) + biases + zero degr/aggr replicas
    prep_weights<<<4092, 256, 0, stream>>>(w_ih0, w_hh0, b_ih0, b_hh0,
                                           w_ih1, w_hh1, b_ih1, b_hh1, pw1,
                                           W0S, W1S, pwS, B0, B1, degr, aggr);
    // 2) degree (XCD-local atomics)
    deg_count<<<(Ee + 255) / 256, 256, 0, stream>>>(ei, degr);
    // 3) dinv
    dinv_kernel<<<(Nn + 255) / 256, 256, 0, stream>>>(degr, dinv);
    // 4) edge scatter: one (edge,t) per thread, 1 independent XCD-local atomic each
    edge_scatter<<<(Ee * Tt + 255) / 256, 256, 0, stream>>>(x, ei, dinv, aggr);

    // 5) fused recurrence (incl. agg fold + dinv[d] + self-loop): LSTM + head
    recur_all<<<Nn / 32, 512, 0, stream>>>(aggr, dinv, gcn_w, gcn_b, W0S, W1S, B0, B1,
                                           pwS, pb1, pw2, pb2, x, out);
}